// Round 3
// baseline (107.319 us; speedup 1.0000x reference)
//
#include <hip/hip_runtime.h>

#define NN 20000
#define VV 100000
#define CC 5000
#define MM 32
#define KK 2048
#define DD 128

// ---------------- K0: active-community table ----------------
__global__ __launch_bounds__(256) void scatter_active_k(const int* __restrict__ cidx,
                                                        int* __restrict__ active) {
  int k = blockIdx.x * 256 + threadIdx.x;
  if (k < KK) active[cidx[k]] = 1;
}

// ---------------- K1: per-community member embedding ----------------
// memb[c][d] = sum_m (valid ? member_score[c][m] : 0) * cemb[n2c[community2node[c][m]]][d]
__global__ __launch_bounds__(128) void member_emb_k(const int* __restrict__ c2n,
    const int* __restrict__ n2c, const float* __restrict__ mscore,
    const int* __restrict__ mnum, const int* __restrict__ active,
    const float* __restrict__ cemb, float* __restrict__ memb) {
  int c = blockIdx.x;
  __shared__ float s_sc[MM];
  __shared__ int s_nc[MM];
  int t = threadIdx.x;  // 0..127 = d
  if (t < MM) {
    int mem = c2n[c * MM + t];
    int nc = n2c[mem];
    bool valid = (t < mnum[c]) && (active[nc] != 0);
    s_nc[t] = nc;
    s_sc[t] = valid ? mscore[c * MM + t] : 0.f;
  }
  __syncthreads();
  float acc = 0.f;
  #pragma unroll
  for (int m = 0; m < MM; ++m) {
    float s = s_sc[m];  // uniform across wave
    if (s != 0.f) acc += s * cemb[(size_t)s_nc[m] * DD + t];
  }
  memb[(size_t)c * DD + t] = acc;
}

// ---------------- K2: fused pred1+pred2+select ----------------
// 512 threads (8 waves), 32 nodes/block. Nodes compacted in-block: active-first.
// pred1: col = tid&127 (1 col/thread), grp = tid>>7 owns rows grp*8..grp*8+7.
//        Wave-uniform skip when the whole 8-row group is inactive.
// pred2: col2 = tid&63, wave w owns rows 4w..4w+3 (hidden dim 64 = one wave).
__global__ __launch_bounds__(512) void fused_k(const float* __restrict__ node_emb,
    const float* __restrict__ cemb, const float* __restrict__ memb,
    const float* __restrict__ W1, const float* __restrict__ b1,
    const float* __restrict__ W2, const float* __restrict__ b2v,
    const float* __restrict__ W3, const float* __restrict__ b3,
    const float* __restrict__ W4, const float* __restrict__ b4v,
    const int* __restrict__ n2c, const int* __restrict__ active,
    const int* __restrict__ nodes, float* __restrict__ out) {
  __shared__ __align__(16) float s_feat[32][388];  // 49.7 KB, padded stride
  __shared__ int s_v[32], s_cm[32], s_perm[32];    // perm: dest row j -> source slot
  __shared__ int s_cnt;
  __shared__ float s_part[4][8][2];                // pred1 partials per col-half
  __shared__ float s_p2[32];
  int tid = threadIdx.x;
  int n0 = blockIdx.x * 32;

  if (tid < 32) {  // wave 0, lanes 0..31
    int v = nodes[n0 + tid];
    int cm = n2c[v];
    s_v[tid] = v; s_cm[tid] = cm;
    int use = active[cm];
    unsigned mm = (unsigned)__ballot(use != 0);   // lanes >=32 inactive -> 0
    int cnt = __popc(mm);
    int below = __popc(mm & ((1u << tid) - 1));
    int pos = use ? below : (cnt + (tid - below));
    s_perm[pos] = tid;
    if (tid == 0) s_cnt = cnt;
  }
  __syncthreads();
  int cnt = s_cnt;

  // ---- stage feat (permuted rows; inactive rows: node_emb part only) ----
  {
    int q = tid >> 7, d = tid & 127;
    #pragma unroll
    for (int jj = 0; jj < 8; ++jj) {
      int j = q * 8 + jj;
      int s = s_perm[j];
      s_feat[j][d] = node_emb[(size_t)(n0 + s) * DD + d];
      if (j < cnt) {  // wave-uniform (j depends on tid>>7 only)
        s_feat[j][DD + d]     = cemb[(size_t)s_v[s] * DD + d];
        s_feat[j][2 * DD + d] = memb[(size_t)s_cm[s] * DD + d];
      }
    }
  }
  __syncthreads();

  // ---- pred2 for all 32 rows (uses feat cols 0..127 = node_emb) ----
  {
    float acc2[4] = {0.f, 0.f, 0.f, 0.f};
    int col2 = tid & 63;
    int w = tid >> 6;
    #pragma unroll 4
    for (int i = 0; i < DD; i += 4) {
      float wv0 = W3[(size_t)(i + 0) * 64 + col2];
      float wv1 = W3[(size_t)(i + 1) * 64 + col2];
      float wv2 = W3[(size_t)(i + 2) * 64 + col2];
      float wv3 = W3[(size_t)(i + 3) * 64 + col2];
      #pragma unroll
      for (int t = 0; t < 4; ++t) {
        float4 f = *(const float4*)&s_feat[w * 4 + t][i];
        acc2[t] += f.x * wv0 + f.y * wv1 + f.z * wv2 + f.w * wv3;
      }
    }
    float b3v = b3[col2], w4v = W4[col2], bias4 = b4v[0];
    #pragma unroll
    for (int t = 0; t < 4; ++t) {
      float p = fmaxf(acc2[t] + b3v, 0.f) * w4v;
      #pragma unroll
      for (int m = 32; m >= 1; m >>= 1) p += __shfl_xor(p, m, 64);
      if (col2 == 0) s_p2[w * 4 + t] = p + bias4;
    }
  }

  // ---- pred1 for active rows only (wave-uniform group skip) ----
  {
    int col = tid & 127;
    int grp = tid >> 7;
    int half = (tid >> 6) & 1;
    if (grp * 8 < cnt) {
      float acc[8];
      #pragma unroll
      for (int s = 0; s < 8; ++s) acc[s] = 0.f;
      #pragma unroll 4
      for (int i = 0; i < 3 * DD; i += 4) {
        float w0 = W1[(size_t)(i + 0) * DD + col];
        float w1 = W1[(size_t)(i + 1) * DD + col];
        float w2 = W1[(size_t)(i + 2) * DD + col];
        float w3 = W1[(size_t)(i + 3) * DD + col];
        #pragma unroll
        for (int s = 0; s < 8; ++s) {
          float4 f = *(const float4*)&s_feat[grp * 8 + s][i];
          acc[s] += f.x * w0 + f.y * w1 + f.z * w2 + f.w * w3;
        }
      }
      float b1v = b1[col], w2v = W2[col];
      #pragma unroll
      for (int s = 0; s < 8; ++s) {
        float p = fmaxf(acc[s] + b1v, 0.f) * w2v;
        #pragma unroll
        for (int m = 32; m >= 1; m >>= 1) p += __shfl_xor(p, m, 64);
        if (col == 0 || col == 64) s_part[grp][s][half] = p;
      }
    }
  }
  __syncthreads();

  // ---- select + write ----
  if (tid < 32) {
    int j = tid;
    int n = n0 + s_perm[j];
    float r;
    if (j < cnt) r = s_part[j >> 3][j & 7][0] + s_part[j >> 3][j & 7][1] + b2v[0];
    else         r = s_p2[j];
    out[n] = r;
  }
}

extern "C" void kernel_launch(void* const* d_in, const int* in_sizes, int n_in,
                              void* d_out, int out_size, void* d_ws, size_t ws_size,
                              hipStream_t stream) {
  const float* node_emb = (const float*)d_in[0];
  const float* mscore   = (const float*)d_in[1];
  const float* cemb     = (const float*)d_in[2];
  const float* W1 = (const float*)d_in[3];
  const float* b1 = (const float*)d_in[4];
  const float* W2 = (const float*)d_in[5];
  const float* b2 = (const float*)d_in[6];
  const float* W3 = (const float*)d_in[7];
  const float* b3 = (const float*)d_in[8];
  const float* W4 = (const float*)d_in[9];
  const float* b4 = (const float*)d_in[10];
  const int* n2c   = (const int*)d_in[11];
  const int* c2n   = (const int*)d_in[12];
  const int* mnum  = (const int*)d_in[13];
  const int* cidx  = (const int*)d_in[14];
  const int* nodes = (const int*)d_in[15];
  float* out = (float*)d_out;

  // workspace layout: active[C] ints at 0; memb[C*D] floats at 32768
  int* active = (int*)d_ws;
  float* memb = (float*)((char*)d_ws + 32768);

  hipMemsetAsync(active, 0, CC * sizeof(int), stream);
  scatter_active_k<<<(KK + 255) / 256, 256, 0, stream>>>(cidx, active);
  member_emb_k<<<CC, 128, 0, stream>>>(c2n, n2c, mscore, mnum, active, cemb, memb);
  fused_k<<<NN / 32, 512, 0, stream>>>(node_emb, cemb, memb, W1, b1, W2, b2,
                                       W3, b3, W4, b4, n2c, active, nodes, out);
}

// Round 4
// 74.747 us; speedup vs baseline: 1.4358x; 1.4358x over previous
//
#include <hip/hip_runtime.h>

#define NN 20000
#define VV 100000
#define CC 5000
#define MM 32
#define KK 2048
#define DD 128

// ws layout: active[C] @0 (20000B); acount @20480; memb @32768 (2.56MB); alist4 @2592768 (320KB)
#define WS_ACOUNT 20480
#define WS_MEMB 32768
#define WS_ALIST 2592768

// ---------------- K0: active-community table ----------------
__global__ __launch_bounds__(256) void scatter_active_k(const int* __restrict__ cidx,
                                                        int* __restrict__ active) {
  int k = blockIdx.x * 256 + threadIdx.x;
  if (k < KK) active[cidx[k]] = 1;
}

// ---------------- K1: per-community member embedding ----------------
__global__ __launch_bounds__(128) void member_emb_k(const int* __restrict__ c2n,
    const int* __restrict__ n2c, const float* __restrict__ mscore,
    const int* __restrict__ mnum, const int* __restrict__ active,
    const float* __restrict__ cemb, float* __restrict__ memb) {
  int c = blockIdx.x;
  __shared__ float s_sc[MM];
  __shared__ int s_nc[MM];
  int t = threadIdx.x;  // 0..127 = d
  if (t < MM) {
    int mem = c2n[c * MM + t];
    int nc = n2c[mem];
    bool valid = (t < mnum[c]) && (active[nc] != 0);
    s_nc[t] = nc;
    s_sc[t] = valid ? mscore[c * MM + t] : 0.f;
  }
  __syncthreads();
  float acc = 0.f;
  #pragma unroll
  for (int m = 0; m < MM; ++m) {
    float s = s_sc[m];
    if (s != 0.f) acc += s * cemb[(size_t)s_nc[m] * DD + t];
  }
  memb[(size_t)c * DD + t] = acc;
}

// ---------------- K2: prep = compaction + pred2 for ALL nodes ----------------
// 256 threads, 32 nodes/block. Wave0 lanes 0-31 classify + compact into alist.
// pred2: col = tid&63, wave w owns rows w*8..w*8+7.
__global__ __launch_bounds__(256) void prep_k(const float* __restrict__ node_emb,
    const float* __restrict__ W3, const float* __restrict__ b3,
    const float* __restrict__ W4, const float* __restrict__ b4v,
    const int* __restrict__ n2c, const int* __restrict__ active,
    const int* __restrict__ nodes, float* __restrict__ out,
    int4* __restrict__ alist, int* __restrict__ acount) {
  __shared__ __align__(16) float s_ne[32][DD];  // 16 KB
  int tid = threadIdx.x;
  int n0 = blockIdx.x * 32;
  {
    const float4* src = (const float4*)(node_emb + (size_t)n0 * DD);
    float4* dst = (float4*)&s_ne[0][0];
    #pragma unroll
    for (int p = 0; p < 4; ++p) dst[tid + 256 * p] = src[tid + 256 * p];
  }
  if (tid < 64) {  // wave 0: compaction
    int lane = tid;
    int use = 0, v = 0, cm = 0, n = n0 + lane;
    if (lane < 32) { v = nodes[n]; cm = n2c[v]; use = active[cm]; }
    unsigned long long bal = __ballot(use != 0);
    int cnt = __popcll(bal);
    int base = 0;
    if (lane == 0) base = atomicAdd(acount, cnt);
    base = __shfl(base, 0, 64);
    if (use) {
      int below = __popcll(bal & ((1ull << (unsigned)lane) - 1ull));
      alist[base + below] = make_int4(n, v, cm, 0);
    }
  }
  __syncthreads();
  // pred2 over staged rows
  int col = tid & 63, w = tid >> 6;
  float acc[8];
  #pragma unroll
  for (int s = 0; s < 8; ++s) acc[s] = 0.f;
  #pragma unroll 4
  for (int i = 0; i < DD; i += 4) {
    float w0 = W3[(size_t)(i + 0) * 64 + col];
    float w1 = W3[(size_t)(i + 1) * 64 + col];
    float w2 = W3[(size_t)(i + 2) * 64 + col];
    float w3 = W3[(size_t)(i + 3) * 64 + col];
    #pragma unroll
    for (int s = 0; s < 8; ++s) {
      float4 f = *(const float4*)&s_ne[w * 8 + s][i];
      acc[s] += f.x * w0 + f.y * w1 + f.z * w2 + f.w * w3;
    }
  }
  float b3v = b3[col], w4v = W4[col], bias = b4v[0];
  #pragma unroll
  for (int s = 0; s < 8; ++s) {
    float p = fmaxf(acc[s] + b3v, 0.f) * w4v;
    #pragma unroll
    for (int m = 32; m >= 1; m >>= 1) p += __shfl_xor(p, m, 64);
    if (col == 0) out[n0 + w * 8 + s] = p + bias;
  }
}

// ---------------- K3: pred1 over compacted active rows ----------------
// 1024 threads, 32 rows/block, split-K in-block:
//   g = tid>>7 (0..7): kh = g&1 (K-half of 192), rq = g>>1 (rows rq*8..rq*8+7), col = tid&127.
// Partials merged via LDS; epilogue ReLU + W2 dot + 64-lane reduce.
__global__ __launch_bounds__(1024) void pred1_k(const float* __restrict__ node_emb,
    const float* __restrict__ cemb, const float* __restrict__ memb,
    const float* __restrict__ W1, const float* __restrict__ b1,
    const float* __restrict__ W2, const float* __restrict__ b2v,
    const int4* __restrict__ alist, const int* __restrict__ acount,
    float* __restrict__ out) {
  __shared__ __align__(16) float s_feat[32][388];       // 49.7 KB
  __shared__ __align__(16) float s_part[2][32][DD];     // 32 KB
  __shared__ int4 s_meta[32];
  __shared__ float s_rsum[32][2];
  int nact = *acount;
  int j0 = blockIdx.x * 32;
  if (j0 >= nact) return;
  int tid = threadIdx.x;
  if (tid < 32) {
    s_meta[tid] = (j0 + tid < nact) ? alist[j0 + tid] : make_int4(0, 0, 0, -1);
  }
  __syncthreads();
  {  // stage feat: 8 groups x 128 threads, 4 rows each
    int d = tid & 127, q = tid >> 7;
    #pragma unroll
    for (int jj = 0; jj < 4; ++jj) {
      int j = q * 4 + jj;
      int4 mt = s_meta[j];
      bool ok = (mt.w == 0);
      s_feat[j][d]          = ok ? node_emb[(size_t)mt.x * DD + d] : 0.f;
      s_feat[j][DD + d]     = ok ? cemb[(size_t)mt.y * DD + d]     : 0.f;
      s_feat[j][2 * DD + d] = ok ? memb[(size_t)mt.z * DD + d]     : 0.f;
    }
  }
  __syncthreads();
  int col = tid & 127, g = tid >> 7, kh = g & 1, rq = g >> 1;
  float acc[8];
  #pragma unroll
  for (int s = 0; s < 8; ++s) acc[s] = 0.f;
  int kbeg = kh * 192;
  #pragma unroll 4
  for (int i = kbeg; i < kbeg + 192; i += 4) {
    float w0 = W1[(size_t)(i + 0) * DD + col];
    float w1 = W1[(size_t)(i + 1) * DD + col];
    float w2 = W1[(size_t)(i + 2) * DD + col];
    float w3 = W1[(size_t)(i + 3) * DD + col];
    #pragma unroll
    for (int s = 0; s < 8; ++s) {
      float4 f = *(const float4*)&s_feat[rq * 8 + s][i];
      acc[s] += f.x * w0 + f.y * w1 + f.z * w2 + f.w * w3;
    }
  }
  #pragma unroll
  for (int s = 0; s < 8; ++s) s_part[kh][rq * 8 + s][col] = acc[s];
  __syncthreads();
  if (tid < 512) {
    int rr = tid >> 7;
    float b1v = b1[col], w2v = W2[col];
    #pragma unroll
    for (int s = 0; s < 8; ++s) {
      int r = rr * 8 + s;
      float h = s_part[0][r][col] + s_part[1][r][col] + b1v;
      float p = fmaxf(h, 0.f) * w2v;
      #pragma unroll
      for (int m = 32; m >= 1; m >>= 1) p += __shfl_xor(p, m, 64);
      if ((tid & 63) == 0) s_rsum[r][(tid >> 6) & 1] = p;
    }
  }
  __syncthreads();
  if (tid < 32) {
    int4 mt = s_meta[tid];
    if (mt.w == 0) out[mt.x] = s_rsum[tid][0] + s_rsum[tid][1] + b2v[0];
  }
}

extern "C" void kernel_launch(void* const* d_in, const int* in_sizes, int n_in,
                              void* d_out, int out_size, void* d_ws, size_t ws_size,
                              hipStream_t stream) {
  const float* node_emb = (const float*)d_in[0];
  const float* cemb     = (const float*)d_in[2];
  const float* W1 = (const float*)d_in[3];
  const float* b1 = (const float*)d_in[4];
  const float* W2 = (const float*)d_in[5];
  const float* b2 = (const float*)d_in[6];
  const float* W3 = (const float*)d_in[7];
  const float* b3 = (const float*)d_in[8];
  const float* W4 = (const float*)d_in[9];
  const float* b4 = (const float*)d_in[10];
  const float* mscore = (const float*)d_in[1];
  const int* n2c   = (const int*)d_in[11];
  const int* c2n   = (const int*)d_in[12];
  const int* mnum  = (const int*)d_in[13];
  const int* cidx  = (const int*)d_in[14];
  const int* nodes = (const int*)d_in[15];
  float* out = (float*)d_out;

  int* active = (int*)d_ws;
  int* acount = (int*)((char*)d_ws + WS_ACOUNT);
  float* memb = (float*)((char*)d_ws + WS_MEMB);
  int4* alist = (int4*)((char*)d_ws + WS_ALIST);

  hipMemsetAsync(d_ws, 0, 32768, stream);  // clears active + acount
  scatter_active_k<<<(KK + 255) / 256, 256, 0, stream>>>(cidx, active);
  member_emb_k<<<CC, 128, 0, stream>>>(c2n, n2c, mscore, mnum, active, cemb, memb);
  prep_k<<<NN / 32, 256, 0, stream>>>(node_emb, W3, b3, W4, b4, n2c, active, nodes,
                                      out, alist, acount);
  pred1_k<<<NN / 32, 1024, 0, stream>>>(node_emb, cemb, memb, W1, b1, W2, b2,
                                        alist, acount, out);
}